// Round 2
// baseline (841.604 us; speedup 1.0000x reference)
//
#include <hip/hip_runtime.h>

#define B 32
#define L 2048
#define H 1024
#define K2 2048            // 2*H

// ---------------------------------------------------------------------------
// v[b,h] = sum_g hs[b,g] * attn_W[g,h]        (32 x 1024)
// grid: 128 blocks x 256 thr; b uniform per block -> hs reads are s_loads.
// ---------------------------------------------------------------------------
__global__ __launch_bounds__(256) void v_kernel(const float* __restrict__ hs,
                                                const float* __restrict__ attn_W,
                                                float* __restrict__ v) {
    int tid = blockIdx.x * 256 + threadIdx.x;   // 0..32767
    int b = tid >> 10;
    int h = tid & (H - 1);
    const float* hsb = hs + b * H;
    float acc = 0.f;
    #pragma unroll 8
    for (int g = 0; g < H; ++g)
        acc = fmaf(hsb[g], attn_W[g * H + h], acc);   // attn_W coalesced
    v[tid] = acc;
}

// ---------------------------------------------------------------------------
// w[b,k] = sum_h v[b,h] * reduce_W[h,k]       (32 x 2048) — single kernel
// grid: 256 blocks (b = blk>>3 uniform, k-slice of 256); rW reads coalesced,
// v reads wave-uniform scalar path. rW slice is L2-resident after first pass.
// ---------------------------------------------------------------------------
__global__ __launch_bounds__(256) void w_kernel(const float* __restrict__ v,
                                                const float* __restrict__ rW,
                                                float* __restrict__ w) {
    int b = blockIdx.x >> 3;
    int k = (blockIdx.x & 7) * 256 + threadIdx.x;
    const float* vb = v + b * H;
    float acc = 0.f;
    #pragma unroll 8
    for (int h = 0; h < H; ++h)
        acc = fmaf(vb[h], rW[h * K2 + k], acc);
    w[b * K2 + k] = acc;
}

// ---------------------------------------------------------------------------
// scores[b,l] = w[b,:] . enc[l,b,:]   -- THE streaming kernel (512 MB read)
// One block per l (contiguous 256 KB slice); wave `wv` owns 8 consecutive b
// rows = contiguous 64 KB. Device-wide access is ~linear (2048 long streams)
// for DRAM row locality. Reduction is wave-local shuffles only.
// ---------------------------------------------------------------------------
__global__ __launch_bounds__(256) void scores_kernel(const float4* __restrict__ enc,
                                                     const float4* __restrict__ w4,
                                                     float* __restrict__ scores) {
    const int l    = blockIdx.x;
    const int wv   = threadIdx.x >> 6;
    const int lane = threadIdx.x & 63;
    const int b0   = wv * 8;                          // 8 b-rows per wave
    const float4* encl = enc + (size_t)l * (B * K2 / 4) + b0 * (K2 / 4);
    const float4* wb0  = w4 + b0 * (K2 / 4);          // L2-resident
    float acc[8];
    #pragma unroll
    for (int i = 0; i < 8; ++i) acc[i] = 0.f;
    #pragma unroll
    for (int i = 0; i < 8; ++i) {                     // b = b0 + i
        const float4* e = encl + i * (K2 / 4);
        const float4* wb = wb0 + i * (K2 / 4);
        #pragma unroll
        for (int it = 0; it < 8; ++it) {              // 512 f4 / 64 lanes
            float4 ev = e[it * 64 + lane];            // contiguous 1 KB/wave
            float4 wvv = wb[it * 64 + lane];
            acc[i] = fmaf(ev.x, wvv.x, acc[i]);
            acc[i] = fmaf(ev.y, wvv.y, acc[i]);
            acc[i] = fmaf(ev.z, wvv.z, acc[i]);
            acc[i] = fmaf(ev.w, wvv.w, acc[i]);
        }
    }
    #pragma unroll
    for (int i = 0; i < 8; ++i) {
        float s = acc[i];
        #pragma unroll
        for (int off = 32; off > 0; off >>= 1) s += __shfl_down(s, off, 64);
        if (lane == 0) scores[(b0 + i) * L + l] = s;
    }
}

// ---------------------------------------------------------------------------
// In-place row softmax over l (row length L=2048), one block per b.
// ---------------------------------------------------------------------------
__global__ __launch_bounds__(256) void softmax_kernel(float* __restrict__ out) {
    int b = blockIdx.x;
    int t = threadIdx.x;
    float* row = out + b * L;
    float vals[8];
    float m = -3.4e38f;
    #pragma unroll
    for (int i = 0; i < 8; ++i) { vals[i] = row[t + i * 256]; m = fmaxf(m, vals[i]); }
    __shared__ float wred[4];
    int wv = t >> 6, lane = t & 63;
    #pragma unroll
    for (int off = 1; off < 64; off <<= 1) m = fmaxf(m, __shfl_xor(m, off, 64));
    if (lane == 0) wred[wv] = m;
    __syncthreads();
    m = fmaxf(fmaxf(wred[0], wred[1]), fmaxf(wred[2], wred[3]));
    __syncthreads();                     // wred reused for the sum
    float s = 0.f;
    #pragma unroll
    for (int i = 0; i < 8; ++i) { vals[i] = __expf(vals[i] - m); s += vals[i]; }
    #pragma unroll
    for (int off = 1; off < 64; off <<= 1) s += __shfl_xor(s, off, 64);
    if (lane == 0) wred[wv] = s;
    __syncthreads();
    s = wred[0] + wred[1] + wred[2] + wred[3];
    float inv = 1.f / s;
    #pragma unroll
    for (int i = 0; i < 8; ++i) row[t + i * 256] = vals[i] * inv;
}

extern "C" void kernel_launch(void* const* d_in, const int* in_sizes, int n_in,
                              void* d_out, int out_size, void* d_ws, size_t ws_size,
                              hipStream_t stream) {
    const float* hs  = (const float*)d_in[0];   // (B,H)
    const float* enc = (const float*)d_in[1];   // (L,B,2H)
    const float* rW  = (const float*)d_in[2];   // (H,2H)
    // d_in[3] = reduce_b : uniform over l -> cancels in softmax
    const float* aW  = (const float*)d_in[4];   // (H,H)
    // d_in[5] = attn_b  : uniform over l -> cancels in softmax
    float* out = (float*)d_out;                 // (B,L) fp32

    char* ws = (char*)d_ws;
    float* v = (float*)(ws);                    // B*H  = 128 KB
    float* w = (float*)(ws + 131072);           // B*K2 = 256 KB

    v_kernel<<<(B * H) / 256, 256, 0, stream>>>(hs, aW, v);
    w_kernel<<<(B * K2) / 256, 256, 0, stream>>>(v, rW, w);
    scores_kernel<<<L, 256, 0, stream>>>((const float4*)enc, (const float4*)w, out);
    softmax_kernel<<<B, 256, 0, stream>>>(out);
}